// Round 14
// baseline (1051.586 us; speedup 1.0000x reference)
//
#include <hip/hip_runtime.h>

// PolicyNetGARCH: B=1024 S=512 OBS=5 NINS=2 H=32 NBLK=4
// Round 14: R13's verified MFMA pipeline (4 waves/WG, wave k = block k,
// super-tick = 2 timesteps, permlane reduces, parity-dbuf LDS handoff,
// exp2-prescaled gates, C/D-layout == B-fragment feedback) with TWO
// independent batch-tile streams per wave (bg and bg+16). Weights/biases
// are shared A-operands; only state/xt registers double. Each wave gets a
// second fully-independent dependency chain -> in-wave latency hiding
// (R13 was chain-bound: 5480 cy/super-tick vs ~1000 cy issue).
// Grid = 32 WGs x 256 thr.

constexpr int B_ = 1024, S_ = 512, OBS_ = 5, NINS_ = 2, H_ = 32, NBLK_ = 4;
constexpr int TT_ = S_ / 2;    // super-ticks
constexpr float EPS_ = 1e-6f;
constexpr float LOG2E_ = 1.4426950408889634f;

typedef __fp16 h2 __attribute__((ext_vector_type(2)));
typedef __fp16 h8 __attribute__((ext_vector_type(8)));
typedef float  f4 __attribute__((ext_vector_type(4)));
typedef int    i4 __attribute__((ext_vector_type(4)));

__device__ __forceinline__ float rcp_(float x) { return __builtin_amdgcn_rcpf(x); }
__device__ __forceinline__ float rsq_(float x) { return __builtin_amdgcn_rsqf(x); }
__device__ __forceinline__ float ex2_(float x) { return __builtin_amdgcn_exp2f(x); }
__device__ __forceinline__ h2 pk_(float a, float b) {
  return __builtin_amdgcn_cvt_pkrtz(a, b);
}
__device__ __forceinline__ h8 pk8_(f4 lo, f4 hi) {
  i4 q;
  q[0] = __builtin_bit_cast(int, pk_(lo[0], lo[1]));
  q[1] = __builtin_bit_cast(int, pk_(lo[2], lo[3]));
  q[2] = __builtin_bit_cast(int, pk_(hi[0], hi[1]));
  q[3] = __builtin_bit_cast(int, pk_(hi[2], hi[3]));
  return __builtin_bit_cast(h8, q);
}
__device__ __forceinline__ f4 mfma_(h8 a, h8 b, f4 c) {
  return __builtin_amdgcn_mfma_f32_16x16x32_f16(a, b, c, 0, 0, 0);
}
__device__ __forceinline__ f4 sg4_(f4 a) {          // sigmoid, log2e-prescaled
  f4 r;
  r[0] = rcp_(1.f + ex2_(-a[0]));
  r[1] = rcp_(1.f + ex2_(-a[1]));
  r[2] = rcp_(1.f + ex2_(-a[2]));
  r[3] = rcp_(1.f + ex2_(-a[3]));
  return r;
}
__device__ __forceinline__ f4 th4_(f4 a) {          // tanh, 2*log2e-prescaled
  f4 r;
  r[0] = fmaf(2.f, rcp_(1.f + ex2_(-a[0])), -1.f);
  r[1] = fmaf(2.f, rcp_(1.f + ex2_(-a[1])), -1.f);
  r[2] = fmaf(2.f, rcp_(1.f + ex2_(-a[2])), -1.f);
  r[3] = fmaf(2.f, rcp_(1.f + ex2_(-a[3])), -1.f);
  return r;
}
__device__ __forceinline__ f4 thc4_(f4 c) {         // tanh of linear c
  constexpr float M = 2.f * LOG2E_;
  f4 r;
  r[0] = fmaf(2.f, rcp_(1.f + ex2_(-M * c[0])), -1.f);
  r[1] = fmaf(2.f, rcp_(1.f + ex2_(-M * c[1])), -1.f);
  r[2] = fmaf(2.f, rcp_(1.f + ex2_(-M * c[2])), -1.f);
  r[3] = fmaf(2.f, rcp_(1.f + ex2_(-M * c[3])), -1.f);
  return r;
}
__device__ __forceinline__ float dot44_(f4 a, f4 x, f4 b2, f4 y) {
  float s = a[0] * x[0];
  s = fmaf(a[1], x[1], s); s = fmaf(a[2], x[2], s); s = fmaf(a[3], x[3], s);
  s = fmaf(b2[0], y[0], s); s = fmaf(b2[1], y[1], s);
  s = fmaf(b2[2], y[2], s); s = fmaf(b2[3], y[3], s);
  return s;
}
// partner across lane^16 (VALU permlane; re = even 16-row)
__device__ __forceinline__ float psw16_(float v, bool re) {
#if __has_builtin(__builtin_amdgcn_permlane16_swap)
  auto r = __builtin_amdgcn_permlane16_swap(
      __builtin_bit_cast(int, v), __builtin_bit_cast(int, v), false, false);
  return __builtin_bit_cast(float, re ? (int)r[1] : (int)r[0]);
#else
  return __shfl_xor(v, 16);
#endif
}
// partner across lane^32 (VALU permlane; lo = lane<32)
__device__ __forceinline__ float psw32_(float v, bool lo) {
#if __has_builtin(__builtin_amdgcn_permlane32_swap)
  auto r = __builtin_amdgcn_permlane32_swap(
      __builtin_bit_cast(int, v), __builtin_bit_cast(int, v), false, false);
  return __builtin_bit_cast(float, lo ? (int)r[1] : (int)r[0]);
#else
  return __shfl_xor(v, 32);
#endif
}

// One LSTM block step for one stream. Uses kernel-scope wx/wh/biasv/
// rw0v/rw1v and re_/lo_. Updates the named state and XT in place.
#define BLK_STEP(C0, C1, HV0, HV1, XT0, XT1) do {                          \
    float _ss = dot44_((XT0), (XT0), (XT1), (XT1));                        \
    _ss += psw16_(_ss, re_);                                               \
    _ss += psw32_(_ss, lo_);                                               \
    const float _rinv = rsq_(_ss * (1.0f / 32.0f) + EPS_);                 \
    const h8 _bx = pk8_((XT0) * rw0v, (XT1) * rw1v);                       \
    const h8 _bh = pk8_((HV0), (HV1));                                     \
    const f4 _z = {};                                                      \
    f4 _ax, _ah, _gi0, _gi1, _gf0, _gf1, _gg0, _gg1, _go0, _go1;           \
    _ax = mfma_(wx[0], _bx, _z); _ah = mfma_(wh[0], _bh, biasv[0]); _gi0 = _ax * _rinv + _ah; \
    _ax = mfma_(wx[1], _bx, _z); _ah = mfma_(wh[1], _bh, biasv[1]); _gi1 = _ax * _rinv + _ah; \
    _ax = mfma_(wx[2], _bx, _z); _ah = mfma_(wh[2], _bh, biasv[2]); _gf0 = _ax * _rinv + _ah; \
    _ax = mfma_(wx[3], _bx, _z); _ah = mfma_(wh[3], _bh, biasv[3]); _gf1 = _ax * _rinv + _ah; \
    _ax = mfma_(wx[4], _bx, _z); _ah = mfma_(wh[4], _bh, biasv[4]); _gg0 = _ax * _rinv + _ah; \
    _ax = mfma_(wx[5], _bx, _z); _ah = mfma_(wh[5], _bh, biasv[5]); _gg1 = _ax * _rinv + _ah; \
    _ax = mfma_(wx[6], _bx, _z); _ah = mfma_(wh[6], _bh, biasv[6]); _go0 = _ax * _rinv + _ah; \
    _ax = mfma_(wx[7], _bx, _z); _ah = mfma_(wh[7], _bh, biasv[7]); _go1 = _ax * _rinv + _ah; \
    const f4 _si0 = sg4_(_gi0), _si1 = sg4_(_gi1);                         \
    const f4 _sf0 = sg4_(_gf0), _sf1 = sg4_(_gf1);                         \
    const f4 _tg0 = th4_(_gg0), _tg1 = th4_(_gg1);                         \
    const f4 _so0 = sg4_(_go0), _so1 = sg4_(_go1);                         \
    (C0) = _sf0 * (C0) + _si0 * _tg0;                                      \
    (C1) = _sf1 * (C1) + _si1 * _tg1;                                      \
    (HV0) = _so0 * thc4_(C0);                                              \
    (HV1) = _so1 * thc4_(C1);                                              \
    (XT0) += (HV0);                                                        \
    (XT1) += (HV1);                                                        \
  } while (0)

__global__ __launch_bounds__(256, 1) void garch_mfma4_kernel(
    const float* __restrict__ obs, const float* __restrict__ prev,
    const float* __restrict__ W_in, const float* __restrict__ b_in,
    const float* __restrict__ rms_w,
    const float* __restrict__ W_ih, const float* __restrict__ W_hh,
    const float* __restrict__ b_ih, const float* __restrict__ b_hh,
    const float* __restrict__ head_w, const float* __restrict__ head_b,
    float* __restrict__ out) {
  const int tid  = threadIdx.x;
  const int k    = tid >> 6;        // wave role == LSTM block
  const int lane = tid & 63;
  const int g    = lane >> 4;       // k-chunk / row group
  const int b    = lane & 15;       // batch column within tile
  const int bg0  = blockIdx.x * 32 + b;        // stream 0
  const int bg1  = bg0 + 16;                   // stream 1
  const bool re_ = ((lane >> 4) & 1) == 0;
  const bool lo_ = (lane < 32);

  // xt handoff: [stage][parity][stream][step][bcol][32 rows + pad]
  __shared__ __align__(16) float xslot[3][2][2][2][16][36];

  // ---- A-fragments / biases for this wave's block (exp2-prescaled) ----
  h8 wx[8], wh[8];
  f4 biasv[8];
  {
    const size_t wb = (size_t)k * 128 * 32;
#pragma unroll
    for (int mi = 0; mi < 8; ++mi) {
      const float scl = (mi == 4 || mi == 5) ? 2.f * LOG2E_ : LOG2E_;
      const int row = 16 * mi + b;
      const float* px = W_ih + wb + (size_t)row * 32;
      f4 x0 = *(const f4*)(px + 4 * g);
      f4 x1 = *(const f4*)(px + 16 + 4 * g);
      wx[mi] = pk8_(x0 * scl, x1 * scl);
      const float* ph = W_hh + wb + (size_t)row * 32;
      f4 h0v = *(const f4*)(ph + 4 * g);
      f4 h1v = *(const f4*)(ph + 16 + 4 * g);
      wh[mi] = pk8_(h0v * scl, h1v * scl);
      f4 bv;
#pragma unroll
      for (int r = 0; r < 4; ++r) {
        const int gr = k * 128 + 16 * mi + 4 * g + r;
        bv[r] = (b_ih[gr] + b_hh[gr]) * scl;
      }
      biasv[mi] = bv;
    }
  }
  f4 rw0v, rw1v;
#pragma unroll
  for (int r = 0; r < 4; ++r) {
    rw0v[r] = rms_w[k * 32 + 4 * g + r];
    rw1v[r] = rms_w[k * 32 + 16 + 4 * g + r];
  }

  // ---- role-specific constants ----
  h8 winA0 = {}, winA1 = {};
  f4 bin0v = {}, bin1v = {};
  const float* ob0 = nullptr; const float* pv0 = nullptr;
  const float* ob1 = nullptr; const float* pv1 = nullptr;
  // stream0 step A/B inputs and prefetch
  float s0A0 = 0.f, s0A1 = 0.f, s0A2 = 0.f, s0A3 = 0.f;
  float s0B0 = 0.f, s0B1 = 0.f, s0B2 = 0.f, s0B3 = 0.f;
  float n0A0 = 0.f, n0A1 = 0.f, n0A2 = 0.f, n0A3 = 0.f;
  float n0B0 = 0.f, n0B1 = 0.f, n0B2 = 0.f, n0B3 = 0.f;
  // stream1
  float s1A0 = 0.f, s1A1 = 0.f, s1A2 = 0.f, s1A3 = 0.f;
  float s1B0 = 0.f, s1B1 = 0.f, s1B2 = 0.f, s1B3 = 0.f;
  float n1A0 = 0.f, n1A1 = 0.f, n1A2 = 0.f, n1A3 = 0.f;
  float n1B0 = 0.f, n1B1 = 0.f, n1B2 = 0.f, n1B3 = 0.f;
  if (k == 0) {
    f4 lo0, lo1; const f4 z = {};
#pragma unroll
    for (int r = 0; r < 4; ++r) {
      const int kk = 4 * g + r;
      lo0[r] = (kk < 7) ? W_in[(size_t)b * 7 + kk] : 0.f;
      lo1[r] = (kk < 7) ? W_in[(size_t)(16 + b) * 7 + kk] : 0.f;
    }
    winA0 = pk8_(lo0, z);
    winA1 = pk8_(lo1, z);
#pragma unroll
    for (int r = 0; r < 4; ++r) {
      bin0v[r] = b_in[4 * g + r];
      bin1v[r] = b_in[16 + 4 * g + r];
    }
    ob0 = obs  + (size_t)bg0 * S_ * OBS_;
    pv0 = prev + (size_t)bg0 * S_ * NINS_;
    ob1 = obs  + (size_t)bg1 * S_ * OBS_;
    pv1 = prev + (size_t)bg1 * S_ * NINS_;
    if (g == 0) {
      s0A0 = ob0[0]; s0A1 = ob0[1]; s0A2 = ob0[2]; s0A3 = ob0[3];
      s0B0 = ob0[5]; s0B1 = ob0[6]; s0B2 = ob0[7]; s0B3 = ob0[8];
      s1A0 = ob1[0]; s1A1 = ob1[1]; s1A2 = ob1[2]; s1A3 = ob1[3];
      s1B0 = ob1[5]; s1B1 = ob1[6]; s1B2 = ob1[7]; s1B3 = ob1[8];
    } else if (g == 1) {
      s0A0 = ob0[4]; s0A1 = pv0[0]; s0A2 = pv0[1]; s0A3 = 0.f;
      s0B0 = ob0[9]; s0B1 = pv0[2]; s0B2 = pv0[3]; s0B3 = 0.f;
      s1A0 = ob1[4]; s1A1 = pv1[0]; s1A2 = pv1[1]; s1A3 = 0.f;
      s1B0 = ob1[9]; s1B1 = pv1[2]; s1B2 = pv1[3]; s1B3 = 0.f;
    }
  }
  f4 hw00 = {}, hw01 = {}, hw10 = {}, hw11 = {};
  float hb0 = 0.f, hb1 = 0.f;
  if (k == 3) {
#pragma unroll
    for (int r = 0; r < 4; ++r) {
      hw00[r] = head_w[4 * g + r]      * LOG2E_;
      hw01[r] = head_w[16 + 4 * g + r] * LOG2E_;
      hw10[r] = head_w[32 + 4 * g + r] * LOG2E_;
      hw11[r] = head_w[48 + 4 * g + r] * LOG2E_;
    }
    hb0 = head_b[0] * LOG2E_;
    hb1 = head_b[1] * LOG2E_;
  }

  // per-stream block state
  f4 c00 = {}, c01 = {}, h00 = {}, h01 = {};   // stream 0
  f4 c10 = {}, c11 = {}, h10 = {}, h11 = {};   // stream 1

  float* out_y  = out;                                // [2][B][S]
  float* out_hT = out + (size_t)NINS_ * B_ * S_;      // [4][B][H]
  float* out_cT = out_hT + (size_t)NBLK_ * B_ * H_;   // [4][B][H]

  for (int tau = 0; tau < TT_ + NBLK_ - 1; ++tau) {
    __syncthreads();
    const int tt = tau - k;           // wave-uniform super-tick window
    if (tt < 0 || tt >= TT_) continue;
    const int t0 = 2 * tt;
    const int wp = tau & 1, rp = (tau + 1) & 1;

    // ---- 1. xt tiles: 2 streams x 2 steps x 2 tiles ----
    f4 xA00, xA01, xB00, xB01;   // stream0 stepA/B, tiles 0/1
    f4 xA10, xA11, xB10, xB11;   // stream1
    if (k == 0) {
      if (tt + 1 < TT_) {
        const float* oA0 = ob0 + (size_t)(t0 + 2) * OBS_;
        const float* oB0 = ob0 + (size_t)(t0 + 3) * OBS_;
        const float* oA1 = ob1 + (size_t)(t0 + 2) * OBS_;
        const float* oB1 = ob1 + (size_t)(t0 + 3) * OBS_;
        if (g == 0) {
          n0A0 = oA0[0]; n0A1 = oA0[1]; n0A2 = oA0[2]; n0A3 = oA0[3];
          n0B0 = oB0[0]; n0B1 = oB0[1]; n0B2 = oB0[2]; n0B3 = oB0[3];
          n1A0 = oA1[0]; n1A1 = oA1[1]; n1A2 = oA1[2]; n1A3 = oA1[3];
          n1B0 = oB1[0]; n1B1 = oB1[1]; n1B2 = oB1[2]; n1B3 = oB1[3];
        } else if (g == 1) {
          n0A0 = oA0[4]; n0A1 = pv0[2 * (t0 + 2)]; n0A2 = pv0[2 * (t0 + 2) + 1]; n0A3 = 0.f;
          n0B0 = oB0[4]; n0B1 = pv0[2 * (t0 + 3)]; n0B2 = pv0[2 * (t0 + 3) + 1]; n0B3 = 0.f;
          n1A0 = oA1[4]; n1A1 = pv1[2 * (t0 + 2)]; n1A2 = pv1[2 * (t0 + 2) + 1]; n1A3 = 0.f;
          n1B0 = oB1[4]; n1B1 = pv1[2 * (t0 + 3)]; n1B2 = pv1[2 * (t0 + 3) + 1]; n1B3 = 0.f;
        }
      }
      const f4 z = {};
      const f4 lA0 = { s0A0, s0A1, s0A2, s0A3 };
      const f4 lB0 = { s0B0, s0B1, s0B2, s0B3 };
      const f4 lA1 = { s1A0, s1A1, s1A2, s1A3 };
      const f4 lB1 = { s1B0, s1B1, s1B2, s1B3 };
      const h8 bA0 = pk8_(lA0, z);
      const h8 bB0 = pk8_(lB0, z);
      const h8 bA1 = pk8_(lA1, z);
      const h8 bB1 = pk8_(lB1, z);
      xA00 = mfma_(winA0, bA0, bin0v);
      xA01 = mfma_(winA1, bA0, bin1v);
      xB00 = mfma_(winA0, bB0, bin0v);
      xB01 = mfma_(winA1, bB0, bin1v);
      xA10 = mfma_(winA0, bA1, bin0v);
      xA11 = mfma_(winA1, bA1, bin1v);
      xB10 = mfma_(winA0, bB1, bin0v);
      xB11 = mfma_(winA1, bB1, bin1v);
    } else {
      xA00 = *(const f4*)&xslot[k - 1][rp][0][0][b][4 * g];
      xA01 = *(const f4*)&xslot[k - 1][rp][0][0][b][16 + 4 * g];
      xB00 = *(const f4*)&xslot[k - 1][rp][0][1][b][4 * g];
      xB01 = *(const f4*)&xslot[k - 1][rp][0][1][b][16 + 4 * g];
      xA10 = *(const f4*)&xslot[k - 1][rp][1][0][b][4 * g];
      xA11 = *(const f4*)&xslot[k - 1][rp][1][0][b][16 + 4 * g];
      xB10 = *(const f4*)&xslot[k - 1][rp][1][1][b][4 * g];
      xB11 = *(const f4*)&xslot[k - 1][rp][1][1][b][16 + 4 * g];
    }

    // ---- 2. step A for both streams (independent chains), then step B ----
    BLK_STEP(c00, c01, h00, h01, xA00, xA01);
    BLK_STEP(c10, c11, h10, h11, xA10, xA11);
    BLK_STEP(c00, c01, h00, h01, xB00, xB01);
    BLK_STEP(c10, c11, h10, h11, xB10, xB11);

    // ---- 3. handoff or head ----
    if (k < 3) {
      *(f4*)&xslot[k][wp][0][0][b][4 * g]      = xA00;
      *(f4*)&xslot[k][wp][0][0][b][16 + 4 * g] = xA01;
      *(f4*)&xslot[k][wp][0][1][b][4 * g]      = xB00;
      *(f4*)&xslot[k][wp][0][1][b][16 + 4 * g] = xB01;
      *(f4*)&xslot[k][wp][1][0][b][4 * g]      = xA10;
      *(f4*)&xslot[k][wp][1][0][b][16 + 4 * g] = xA11;
      *(f4*)&xslot[k][wp][1][1][b][4 * g]      = xB10;
      *(f4*)&xslot[k][wp][1][1][b][16 + 4 * g] = xB11;
    } else {
      float p0A0 = dot44_(hw00, xA00, hw01, xA01);
      float p1A0 = dot44_(hw10, xA00, hw11, xA01);
      float p0B0 = dot44_(hw00, xB00, hw01, xB01);
      float p1B0 = dot44_(hw10, xB00, hw11, xB01);
      float p0A1 = dot44_(hw00, xA10, hw01, xA11);
      float p1A1 = dot44_(hw10, xA10, hw11, xA11);
      float p0B1 = dot44_(hw00, xB10, hw01, xB11);
      float p1B1 = dot44_(hw10, xB10, hw11, xB11);
      p0A0 += psw16_(p0A0, re_); p0A0 += psw32_(p0A0, lo_);
      p1A0 += psw16_(p1A0, re_); p1A0 += psw32_(p1A0, lo_);
      p0B0 += psw16_(p0B0, re_); p0B0 += psw32_(p0B0, lo_);
      p1B0 += psw16_(p1B0, re_); p1B0 += psw32_(p1B0, lo_);
      p0A1 += psw16_(p0A1, re_); p0A1 += psw32_(p0A1, lo_);
      p1A1 += psw16_(p1A1, re_); p1A1 += psw32_(p1A1, lo_);
      p0B1 += psw16_(p0B1, re_); p0B1 += psw32_(p0B1, lo_);
      p1B1 += psw16_(p1B1, re_); p1B1 += psw32_(p1B1, lo_);
      p0A0 += hb0; p1A0 += hb1; p0B0 += hb0; p1B0 += hb1;
      p0A1 += hb0; p1A1 += hb1; p0B1 += hb0; p1B1 += hb1;
      if (lane < 16) {
        const float v0A0 = copysignf(fminf(ex2_(fabsf(p0A0)) - 1.f, 5.f),  p0A0);
        const float v0B0 = copysignf(fminf(ex2_(fabsf(p0B0)) - 1.f, 5.f),  p0B0);
        const float v1A0 = copysignf(fminf(ex2_(fabsf(p1A0)) - 1.f, 10.f), p1A0);
        const float v1B0 = copysignf(fminf(ex2_(fabsf(p1B0)) - 1.f, 10.f), p1B0);
        const float v0A1 = copysignf(fminf(ex2_(fabsf(p0A1)) - 1.f, 5.f),  p0A1);
        const float v0B1 = copysignf(fminf(ex2_(fabsf(p0B1)) - 1.f, 5.f),  p0B1);
        const float v1A1 = copysignf(fminf(ex2_(fabsf(p1A1)) - 1.f, 10.f), p1A1);
        const float v1B1 = copysignf(fminf(ex2_(fabsf(p1B1)) - 1.f, 10.f), p1B1);
        *(float2*)&out_y[(size_t)bg0 * S_ + t0]                   = make_float2(v0A0, v0B0);
        *(float2*)&out_y[(size_t)B_ * S_ + (size_t)bg0 * S_ + t0] = make_float2(v1A0, v1B0);
        *(float2*)&out_y[(size_t)bg1 * S_ + t0]                   = make_float2(v0A1, v0B1);
        *(float2*)&out_y[(size_t)B_ * S_ + (size_t)bg1 * S_ + t0] = make_float2(v1A1, v1B1);
      }
    }

    // ---- 4. final states ----
    if (tt == TT_ - 1) {
      float* hp0 = out_hT + ((size_t)k * B_ + bg0) * H_;
      float* cp0 = out_cT + ((size_t)k * B_ + bg0) * H_;
      float* hp1 = out_hT + ((size_t)k * B_ + bg1) * H_;
      float* cp1 = out_cT + ((size_t)k * B_ + bg1) * H_;
#pragma unroll
      for (int r = 0; r < 4; ++r) {
        hp0[4 * g + r]      = h00[r];
        hp0[16 + 4 * g + r] = h01[r];
        cp0[4 * g + r]      = c00[r];
        cp0[16 + 4 * g + r] = c01[r];
        hp1[4 * g + r]      = h10[r];
        hp1[16 + 4 * g + r] = h11[r];
        cp1[4 * g + r]      = c10[r];
        cp1[16 + 4 * g + r] = c11[r];
      }
    }

    if (k == 0) {
      s0A0 = n0A0; s0A1 = n0A1; s0A2 = n0A2; s0A3 = n0A3;
      s0B0 = n0B0; s0B1 = n0B1; s0B2 = n0B2; s0B3 = n0B3;
      s1A0 = n1A0; s1A1 = n1A1; s1A2 = n1A2; s1A3 = n1A3;
      s1B0 = n1B0; s1B1 = n1B1; s1B2 = n1B2; s1B3 = n1B3;
    }
  }
}

extern "C" void kernel_launch(void* const* d_in, const int* in_sizes, int n_in,
                              void* d_out, int out_size, void* d_ws, size_t ws_size,
                              hipStream_t stream) {
  (void)in_sizes; (void)n_in; (void)d_ws; (void)ws_size; (void)out_size;
  garch_mfma4_kernel<<<dim3(B_ / 32), dim3(256), 0, stream>>>(
      (const float*)d_in[0],  // obs_sequence [B,S,OBS]
      (const float*)d_in[1],  // prev_actions [B,S,NINS]
      (const float*)d_in[2],  // W_in [H, OBS+NINS]
      (const float*)d_in[3],  // b_in [H]
      (const float*)d_in[4],  // rms_w [NBLK,H]
      (const float*)d_in[5],  // W_ih [NBLK,4H,H]
      (const float*)d_in[6],  // W_hh [NBLK,4H,H]
      (const float*)d_in[7],  // b_ih [NBLK,4H]
      (const float*)d_in[8],  // b_hh [NBLK,4H]
      (const float*)d_in[9],  // head_w [NINS,H]
      (const float*)d_in[10], // head_b [NINS]
      (float*)d_out);
}

// Round 15
// 875.152 us; speedup vs baseline: 1.2016x; 1.2016x over previous
//
#include <hip/hip_runtime.h>

// PolicyNetGARCH: B=1024 S=512 OBS=5 NINS=2 H=32 NBLK=4
// Round 15: R13's verified MFMA pipeline, with TWO independent column-tile
// pipelines per WG (512 thr = 8 waves; waves 0-3 = tile A stages 0-3,
// waves 4-7 = tile B stages 0-3). HW round-robins waves onto SIMDs, so each
// SIMD gets one wave from EACH pipeline -> 2 independent instruction
// streams per SIMD (TLP) fill each other's dependency-latency gaps.
// R14 tried 2 chains inside one wave (ILP) and failed (tick 5480->9600cy,
// chains serialized); TLP is hardware-interleaved, no scheduling risk.
// Everything else == R13: super-tick = 2 timesteps, skewed 4-stage pipeline,
// parity-dbuf LDS handoff, permlane16/32 reduces, exp2-prescaled gates,
// C/D-layout == B-fragment feedback (verified R11-R13).

constexpr int B_ = 1024, S_ = 512, OBS_ = 5, NINS_ = 2, H_ = 32, NBLK_ = 4;
constexpr int TT_ = S_ / 2;    // super-ticks
constexpr float EPS_ = 1e-6f;
constexpr float LOG2E_ = 1.4426950408889634f;

typedef __fp16 h2 __attribute__((ext_vector_type(2)));
typedef __fp16 h8 __attribute__((ext_vector_type(8)));
typedef float  f4 __attribute__((ext_vector_type(4)));
typedef int    i4 __attribute__((ext_vector_type(4)));

__device__ __forceinline__ float rcp_(float x) { return __builtin_amdgcn_rcpf(x); }
__device__ __forceinline__ float rsq_(float x) { return __builtin_amdgcn_rsqf(x); }
__device__ __forceinline__ float ex2_(float x) { return __builtin_amdgcn_exp2f(x); }
__device__ __forceinline__ h2 pk_(float a, float b) {
  return __builtin_amdgcn_cvt_pkrtz(a, b);
}
__device__ __forceinline__ h8 pk8_(f4 lo, f4 hi) {
  i4 q;
  q[0] = __builtin_bit_cast(int, pk_(lo[0], lo[1]));
  q[1] = __builtin_bit_cast(int, pk_(lo[2], lo[3]));
  q[2] = __builtin_bit_cast(int, pk_(hi[0], hi[1]));
  q[3] = __builtin_bit_cast(int, pk_(hi[2], hi[3]));
  return __builtin_bit_cast(h8, q);
}
__device__ __forceinline__ f4 mfma_(h8 a, h8 b, f4 c) {
  return __builtin_amdgcn_mfma_f32_16x16x32_f16(a, b, c, 0, 0, 0);
}
__device__ __forceinline__ f4 sg4_(f4 a) {          // sigmoid, log2e-prescaled
  f4 r;
  r[0] = rcp_(1.f + ex2_(-a[0]));
  r[1] = rcp_(1.f + ex2_(-a[1]));
  r[2] = rcp_(1.f + ex2_(-a[2]));
  r[3] = rcp_(1.f + ex2_(-a[3]));
  return r;
}
__device__ __forceinline__ f4 th4_(f4 a) {          // tanh, 2*log2e-prescaled
  f4 r;
  r[0] = fmaf(2.f, rcp_(1.f + ex2_(-a[0])), -1.f);
  r[1] = fmaf(2.f, rcp_(1.f + ex2_(-a[1])), -1.f);
  r[2] = fmaf(2.f, rcp_(1.f + ex2_(-a[2])), -1.f);
  r[3] = fmaf(2.f, rcp_(1.f + ex2_(-a[3])), -1.f);
  return r;
}
__device__ __forceinline__ f4 thc4_(f4 c) {         // tanh of linear c
  constexpr float M = 2.f * LOG2E_;
  f4 r;
  r[0] = fmaf(2.f, rcp_(1.f + ex2_(-M * c[0])), -1.f);
  r[1] = fmaf(2.f, rcp_(1.f + ex2_(-M * c[1])), -1.f);
  r[2] = fmaf(2.f, rcp_(1.f + ex2_(-M * c[2])), -1.f);
  r[3] = fmaf(2.f, rcp_(1.f + ex2_(-M * c[3])), -1.f);
  return r;
}
__device__ __forceinline__ float dot44_(f4 a, f4 x, f4 b2, f4 y) {
  float s = a[0] * x[0];
  s = fmaf(a[1], x[1], s); s = fmaf(a[2], x[2], s); s = fmaf(a[3], x[3], s);
  s = fmaf(b2[0], y[0], s); s = fmaf(b2[1], y[1], s);
  s = fmaf(b2[2], y[2], s); s = fmaf(b2[3], y[3], s);
  return s;
}
// partner across lane^16 (VALU permlane; re = even 16-row)
__device__ __forceinline__ float psw16_(float v, bool re) {
#if __has_builtin(__builtin_amdgcn_permlane16_swap)
  auto r = __builtin_amdgcn_permlane16_swap(
      __builtin_bit_cast(int, v), __builtin_bit_cast(int, v), false, false);
  return __builtin_bit_cast(float, re ? (int)r[1] : (int)r[0]);
#else
  return __shfl_xor(v, 16);
#endif
}
// partner across lane^32 (VALU permlane; lo = lane<32)
__device__ __forceinline__ float psw32_(float v, bool lo) {
#if __has_builtin(__builtin_amdgcn_permlane32_swap)
  auto r = __builtin_amdgcn_permlane32_swap(
      __builtin_bit_cast(int, v), __builtin_bit_cast(int, v), false, false);
  return __builtin_bit_cast(float, lo ? (int)r[1] : (int)r[0]);
#else
  return __shfl_xor(v, 32);
#endif
}

// One LSTM block step (uses kernel-scope wx/wh/biasv/rw0v/rw1v, state
// c0/c1/hv0/hv1, bools re_/lo_). Updates state and XT in place.
#define BLK_STEP(XT0, XT1) do {                                            \
    float _ss = dot44_((XT0), (XT0), (XT1), (XT1));                        \
    _ss += psw16_(_ss, re_);                                               \
    _ss += psw32_(_ss, lo_);                                               \
    const float _rinv = rsq_(_ss * (1.0f / 32.0f) + EPS_);                 \
    const h8 _bx = pk8_((XT0) * rw0v, (XT1) * rw1v);                       \
    const h8 _bh = pk8_(hv0, hv1);                                         \
    const f4 _z = {};                                                      \
    f4 _ax, _ah, _gi0, _gi1, _gf0, _gf1, _gg0, _gg1, _go0, _go1;           \
    _ax = mfma_(wx[0], _bx, _z); _ah = mfma_(wh[0], _bh, biasv[0]); _gi0 = _ax * _rinv + _ah; \
    _ax = mfma_(wx[1], _bx, _z); _ah = mfma_(wh[1], _bh, biasv[1]); _gi1 = _ax * _rinv + _ah; \
    _ax = mfma_(wx[2], _bx, _z); _ah = mfma_(wh[2], _bh, biasv[2]); _gf0 = _ax * _rinv + _ah; \
    _ax = mfma_(wx[3], _bx, _z); _ah = mfma_(wh[3], _bh, biasv[3]); _gf1 = _ax * _rinv + _ah; \
    _ax = mfma_(wx[4], _bx, _z); _ah = mfma_(wh[4], _bh, biasv[4]); _gg0 = _ax * _rinv + _ah; \
    _ax = mfma_(wx[5], _bx, _z); _ah = mfma_(wh[5], _bh, biasv[5]); _gg1 = _ax * _rinv + _ah; \
    _ax = mfma_(wx[6], _bx, _z); _ah = mfma_(wh[6], _bh, biasv[6]); _go0 = _ax * _rinv + _ah; \
    _ax = mfma_(wx[7], _bx, _z); _ah = mfma_(wh[7], _bh, biasv[7]); _go1 = _ax * _rinv + _ah; \
    const f4 _si0 = sg4_(_gi0), _si1 = sg4_(_gi1);                         \
    const f4 _sf0 = sg4_(_gf0), _sf1 = sg4_(_gf1);                         \
    const f4 _tg0 = th4_(_gg0), _tg1 = th4_(_gg1);                         \
    const f4 _so0 = sg4_(_go0), _so1 = sg4_(_go1);                         \
    c0 = _sf0 * c0 + _si0 * _tg0;                                          \
    c1 = _sf1 * c1 + _si1 * _tg1;                                          \
    hv0 = _so0 * thc4_(c0);                                                \
    hv1 = _so1 * thc4_(c1);                                                \
    (XT0) += hv0;                                                          \
    (XT1) += hv1;                                                          \
  } while (0)

__global__ __launch_bounds__(512, 1) void garch_mfma5_kernel(
    const float* __restrict__ obs, const float* __restrict__ prev,
    const float* __restrict__ W_in, const float* __restrict__ b_in,
    const float* __restrict__ rms_w,
    const float* __restrict__ W_ih, const float* __restrict__ W_hh,
    const float* __restrict__ b_ih, const float* __restrict__ b_hh,
    const float* __restrict__ head_w, const float* __restrict__ head_b,
    float* __restrict__ out) {
  const int tid  = threadIdx.x;
  const int pipe = tid >> 8;        // which column-tile pipeline (0/1)
  const int k    = (tid >> 6) & 3;  // pipeline stage == LSTM block
  const int lane = tid & 63;
  const int g    = lane >> 4;       // k-chunk / row group
  const int b    = lane & 15;       // batch column within tile
  const int bg   = blockIdx.x * 32 + pipe * 16 + b;
  const bool re_ = ((lane >> 4) & 1) == 0;
  const bool lo_ = (lane < 32);

  // xt handoff per pipeline: [pipe][stage][parity][step][bcol][32 rows+pad]
  __shared__ __align__(16) float xslot[2][3][2][2][16][36];

  // ---- A-fragments / biases for this wave's block (exp2-prescaled) ----
  h8 wx[8], wh[8];
  f4 biasv[8];
  {
    const size_t wb = (size_t)k * 128 * 32;
#pragma unroll
    for (int mi = 0; mi < 8; ++mi) {
      const float scl = (mi == 4 || mi == 5) ? 2.f * LOG2E_ : LOG2E_;
      const int row = 16 * mi + b;
      const float* px = W_ih + wb + (size_t)row * 32;
      f4 x0 = *(const f4*)(px + 4 * g);
      f4 x1 = *(const f4*)(px + 16 + 4 * g);
      wx[mi] = pk8_(x0 * scl, x1 * scl);
      const float* ph = W_hh + wb + (size_t)row * 32;
      f4 h0v = *(const f4*)(ph + 4 * g);
      f4 h1v = *(const f4*)(ph + 16 + 4 * g);
      wh[mi] = pk8_(h0v * scl, h1v * scl);
      f4 bv;
#pragma unroll
      for (int r = 0; r < 4; ++r) {
        const int gr = k * 128 + 16 * mi + 4 * g + r;
        bv[r] = (b_ih[gr] + b_hh[gr]) * scl;
      }
      biasv[mi] = bv;
    }
  }
  f4 rw0v, rw1v;
#pragma unroll
  for (int r = 0; r < 4; ++r) {
    rw0v[r] = rms_w[k * 32 + 4 * g + r];
    rw1v[r] = rms_w[k * 32 + 16 + 4 * g + r];
  }

  // ---- role-specific constants ----
  h8 winA0 = {}, winA1 = {};
  f4 bin0v = {}, bin1v = {};
  const float* obs_b = nullptr; const float* prev_b = nullptr;
  float cA0 = 0.f, cA1 = 0.f, cA2 = 0.f, cA3 = 0.f;   // step-A inputs
  float cB0 = 0.f, cB1 = 0.f, cB2 = 0.f, cB3 = 0.f;   // step-B inputs
  float nA0 = 0.f, nA1 = 0.f, nA2 = 0.f, nA3 = 0.f;
  float nB0 = 0.f, nB1 = 0.f, nB2 = 0.f, nB3 = 0.f;
  if (k == 0) {
    f4 lo0, lo1; const f4 z = {};
#pragma unroll
    for (int r = 0; r < 4; ++r) {
      const int kk = 4 * g + r;
      lo0[r] = (kk < 7) ? W_in[(size_t)b * 7 + kk] : 0.f;
      lo1[r] = (kk < 7) ? W_in[(size_t)(16 + b) * 7 + kk] : 0.f;
    }
    winA0 = pk8_(lo0, z);
    winA1 = pk8_(lo1, z);
#pragma unroll
    for (int r = 0; r < 4; ++r) {
      bin0v[r] = b_in[4 * g + r];
      bin1v[r] = b_in[16 + 4 * g + r];
    }
    obs_b  = obs  + (size_t)bg * S_ * OBS_;
    prev_b = prev + (size_t)bg * S_ * NINS_;
    if (g == 0) {
      cA0 = obs_b[0]; cA1 = obs_b[1]; cA2 = obs_b[2]; cA3 = obs_b[3];
      cB0 = obs_b[5]; cB1 = obs_b[6]; cB2 = obs_b[7]; cB3 = obs_b[8];
    } else if (g == 1) {
      cA0 = obs_b[4]; cA1 = prev_b[0]; cA2 = prev_b[1]; cA3 = 0.f;
      cB0 = obs_b[9]; cB1 = prev_b[2]; cB2 = prev_b[3]; cB3 = 0.f;
    }
  }
  f4 hw00 = {}, hw01 = {}, hw10 = {}, hw11 = {};
  float hb0 = 0.f, hb1 = 0.f;
  if (k == 3) {
#pragma unroll
    for (int r = 0; r < 4; ++r) {
      hw00[r] = head_w[4 * g + r]      * LOG2E_;
      hw01[r] = head_w[16 + 4 * g + r] * LOG2E_;
      hw10[r] = head_w[32 + 4 * g + r] * LOG2E_;
      hw11[r] = head_w[48 + 4 * g + r] * LOG2E_;
    }
    hb0 = head_b[0] * LOG2E_;
    hb1 = head_b[1] * LOG2E_;
  }

  // block state
  f4 c0 = {}, c1 = {}, hv0 = {}, hv1 = {};

  float* out_y  = out;                                // [2][B][S]
  float* out_hT = out + (size_t)NINS_ * B_ * S_;      // [4][B][H]
  float* out_cT = out_hT + (size_t)NBLK_ * B_ * H_;   // [4][B][H]

  for (int tau = 0; tau < TT_ + NBLK_ - 1; ++tau) {
    __syncthreads();
    const int tt = tau - k;           // wave-uniform super-tick window
    if (tt < 0 || tt >= TT_) continue;
    const int t0 = 2 * tt;
    const int wp = tau & 1, rp = (tau + 1) & 1;

    // ---- 1. xt tiles for both timesteps ----
    f4 xtA0, xtA1, xtB0, xtB1;
    if (k == 0) {
      if (tt + 1 < TT_) {             // prefetch next super-tick's inputs
        const float* oA = obs_b + (size_t)(t0 + 2) * OBS_;
        const float* oB = obs_b + (size_t)(t0 + 3) * OBS_;
        if (g == 0) {
          nA0 = oA[0]; nA1 = oA[1]; nA2 = oA[2]; nA3 = oA[3];
          nB0 = oB[0]; nB1 = oB[1]; nB2 = oB[2]; nB3 = oB[3];
        } else if (g == 1) {
          nA0 = oA[4]; nA1 = prev_b[2 * (t0 + 2)]; nA2 = prev_b[2 * (t0 + 2) + 1]; nA3 = 0.f;
          nB0 = oB[4]; nB1 = prev_b[2 * (t0 + 3)]; nB2 = prev_b[2 * (t0 + 3) + 1]; nB3 = 0.f;
        }
      }
      const f4 z = {};
      const f4 loA = { cA0, cA1, cA2, cA3 };
      const f4 loB = { cB0, cB1, cB2, cB3 };
      const h8 binA = pk8_(loA, z);
      const h8 binB = pk8_(loB, z);
      xtA0 = mfma_(winA0, binA, bin0v);
      xtA1 = mfma_(winA1, binA, bin1v);
      xtB0 = mfma_(winA0, binB, bin0v);
      xtB1 = mfma_(winA1, binB, bin1v);
    } else {
      xtA0 = *(const f4*)&xslot[pipe][k - 1][rp][0][b][4 * g];
      xtA1 = *(const f4*)&xslot[pipe][k - 1][rp][0][b][16 + 4 * g];
      xtB0 = *(const f4*)&xslot[pipe][k - 1][rp][1][b][4 * g];
      xtB1 = *(const f4*)&xslot[pipe][k - 1][rp][1][b][16 + 4 * g];
    }

    // ---- 2. two timesteps of this wave's block ----
    BLK_STEP(xtA0, xtA1);
    BLK_STEP(xtB0, xtB1);

    // ---- 3. handoff or head ----
    if (k < 3) {
      *(f4*)&xslot[pipe][k][wp][0][b][4 * g]      = xtA0;
      *(f4*)&xslot[pipe][k][wp][0][b][16 + 4 * g] = xtA1;
      *(f4*)&xslot[pipe][k][wp][1][b][4 * g]      = xtB0;
      *(f4*)&xslot[pipe][k][wp][1][b][16 + 4 * g] = xtB1;
    } else {
      float p0A = dot44_(hw00, xtA0, hw01, xtA1);
      float p1A = dot44_(hw10, xtA0, hw11, xtA1);
      float p0B = dot44_(hw00, xtB0, hw01, xtB1);
      float p1B = dot44_(hw10, xtB0, hw11, xtB1);
      p0A += psw16_(p0A, re_); p0A += psw32_(p0A, lo_);
      p1A += psw16_(p1A, re_); p1A += psw32_(p1A, lo_);
      p0B += psw16_(p0B, re_); p0B += psw32_(p0B, lo_);
      p1B += psw16_(p1B, re_); p1B += psw32_(p1B, lo_);
      p0A += hb0; p1A += hb1; p0B += hb0; p1B += hb1;
      if (lane < 16) {
        const float v0A = copysignf(fminf(ex2_(fabsf(p0A)) - 1.f, 5.f),  p0A);
        const float v0B = copysignf(fminf(ex2_(fabsf(p0B)) - 1.f, 5.f),  p0B);
        const float v1A = copysignf(fminf(ex2_(fabsf(p1A)) - 1.f, 10.f), p1A);
        const float v1B = copysignf(fminf(ex2_(fabsf(p1B)) - 1.f, 10.f), p1B);
        *(float2*)&out_y[(size_t)bg * S_ + t0]                   = make_float2(v0A, v0B);
        *(float2*)&out_y[(size_t)B_ * S_ + (size_t)bg * S_ + t0] = make_float2(v1A, v1B);
      }
    }

    // ---- 4. final states (t = S-1 is step B of the last super-tick) ----
    if (tt == TT_ - 1) {
      float* hp = out_hT + ((size_t)k * B_ + bg) * H_;
      float* cp = out_cT + ((size_t)k * B_ + bg) * H_;
#pragma unroll
      for (int r = 0; r < 4; ++r) {
        hp[4 * g + r]      = hv0[r];
        hp[16 + 4 * g + r] = hv1[r];
        cp[4 * g + r]      = c0[r];
        cp[16 + 4 * g + r] = c1[r];
      }
    }

    if (k == 0) {
      cA0 = nA0; cA1 = nA1; cA2 = nA2; cA3 = nA3;
      cB0 = nB0; cB1 = nB1; cB2 = nB2; cB3 = nB3;
    }
  }
}

extern "C" void kernel_launch(void* const* d_in, const int* in_sizes, int n_in,
                              void* d_out, int out_size, void* d_ws, size_t ws_size,
                              hipStream_t stream) {
  (void)in_sizes; (void)n_in; (void)d_ws; (void)ws_size; (void)out_size;
  garch_mfma5_kernel<<<dim3(B_ / 32), dim3(512), 0, stream>>>(
      (const float*)d_in[0],  // obs_sequence [B,S,OBS]
      (const float*)d_in[1],  // prev_actions [B,S,NINS]
      (const float*)d_in[2],  // W_in [H, OBS+NINS]
      (const float*)d_in[3],  // b_in [H]
      (const float*)d_in[4],  // rms_w [NBLK,H]
      (const float*)d_in[5],  // W_ih [NBLK,4H,H]
      (const float*)d_in[6],  // W_hh [NBLK,4H,H]
      (const float*)d_in[7],  // b_ih [NBLK,4H]
      (const float*)d_in[8],  // b_hh [NBLK,4H]
      (const float*)d_in[9],  // head_w [NINS,H]
      (const float*)d_in[10], // head_b [NINS]
      (float*)d_out);
}

// Round 16
// 465.799 us; speedup vs baseline: 2.2576x; 1.8788x over previous
//
#include <hip/hip_runtime.h>

// PolicyNetGARCH: B=1024 S=512 OBS=5 NINS=2 H=32 NBLK=4
// Round 16: R13's structure EXACTLY (64 WGs x 4 stage-waves = 256 SIMDs;
// wave k = LSTM block k; skewed pipeline; parity-dbuf LDS handoff;
// permlane16/32 reduces; exp2-prescaled gates; verified C/D==B-fragment
// feedback), with per-tick overhead cut:
//  (1) super-tick = 4 timesteps per barrier (259 -> 131 barriers),
//  (2) rinv folded BEFORE the f16 pack (B = normalized xn), and the x-MFMA
//      chained with C = h-MFMA output (bias rides as C of h-MFMA) -> the
//      32-fma gate combine and zero-C disappear; h-MFMAs issue during the
//      RMS reduce,
//  (3) head stores as float4 (4 timesteps per store).

constexpr int B_ = 1024, S_ = 512, OBS_ = 5, NINS_ = 2, H_ = 32, NBLK_ = 4;
constexpr int SUP_ = 4;           // timesteps per super-tick
constexpr int TT_ = S_ / SUP_;    // super-ticks = 128
constexpr float EPS_ = 1e-6f;
constexpr float LOG2E_ = 1.4426950408889634f;

typedef __fp16 h2 __attribute__((ext_vector_type(2)));
typedef __fp16 h8 __attribute__((ext_vector_type(8)));
typedef float  f4 __attribute__((ext_vector_type(4)));
typedef int    i4 __attribute__((ext_vector_type(4)));

__device__ __forceinline__ float rcp_(float x) { return __builtin_amdgcn_rcpf(x); }
__device__ __forceinline__ float rsq_(float x) { return __builtin_amdgcn_rsqf(x); }
__device__ __forceinline__ float ex2_(float x) { return __builtin_amdgcn_exp2f(x); }
__device__ __forceinline__ h2 pk_(float a, float b) {
  return __builtin_amdgcn_cvt_pkrtz(a, b);
}
__device__ __forceinline__ h8 pk8_(f4 lo, f4 hi) {
  i4 q;
  q[0] = __builtin_bit_cast(int, pk_(lo[0], lo[1]));
  q[1] = __builtin_bit_cast(int, pk_(lo[2], lo[3]));
  q[2] = __builtin_bit_cast(int, pk_(hi[0], hi[1]));
  q[3] = __builtin_bit_cast(int, pk_(hi[2], hi[3]));
  return __builtin_bit_cast(h8, q);
}
__device__ __forceinline__ f4 mfma_(h8 a, h8 b, f4 c) {
  return __builtin_amdgcn_mfma_f32_16x16x32_f16(a, b, c, 0, 0, 0);
}
__device__ __forceinline__ f4 sg4_(f4 a) {          // sigmoid, log2e-prescaled
  f4 r;
  r[0] = rcp_(1.f + ex2_(-a[0]));
  r[1] = rcp_(1.f + ex2_(-a[1]));
  r[2] = rcp_(1.f + ex2_(-a[2]));
  r[3] = rcp_(1.f + ex2_(-a[3]));
  return r;
}
__device__ __forceinline__ f4 th4_(f4 a) {          // tanh, 2*log2e-prescaled
  f4 r;
  r[0] = fmaf(2.f, rcp_(1.f + ex2_(-a[0])), -1.f);
  r[1] = fmaf(2.f, rcp_(1.f + ex2_(-a[1])), -1.f);
  r[2] = fmaf(2.f, rcp_(1.f + ex2_(-a[2])), -1.f);
  r[3] = fmaf(2.f, rcp_(1.f + ex2_(-a[3])), -1.f);
  return r;
}
__device__ __forceinline__ f4 thc4_(f4 c) {         // tanh of linear c
  constexpr float M = 2.f * LOG2E_;
  f4 r;
  r[0] = fmaf(2.f, rcp_(1.f + ex2_(-M * c[0])), -1.f);
  r[1] = fmaf(2.f, rcp_(1.f + ex2_(-M * c[1])), -1.f);
  r[2] = fmaf(2.f, rcp_(1.f + ex2_(-M * c[2])), -1.f);
  r[3] = fmaf(2.f, rcp_(1.f + ex2_(-M * c[3])), -1.f);
  return r;
}
__device__ __forceinline__ float dot44_(f4 a, f4 x, f4 b2, f4 y) {
  float s = a[0] * x[0];
  s = fmaf(a[1], x[1], s); s = fmaf(a[2], x[2], s); s = fmaf(a[3], x[3], s);
  s = fmaf(b2[0], y[0], s); s = fmaf(b2[1], y[1], s);
  s = fmaf(b2[2], y[2], s); s = fmaf(b2[3], y[3], s);
  return s;
}
// partner across lane^16 (VALU permlane; re = even 16-row)
__device__ __forceinline__ float psw16_(float v, bool re) {
#if __has_builtin(__builtin_amdgcn_permlane16_swap)
  auto r = __builtin_amdgcn_permlane16_swap(
      __builtin_bit_cast(int, v), __builtin_bit_cast(int, v), false, false);
  return __builtin_bit_cast(float, re ? (int)r[1] : (int)r[0]);
#else
  return __shfl_xor(v, 16);
#endif
}
// partner across lane^32 (VALU permlane; lo = lane<32)
__device__ __forceinline__ float psw32_(float v, bool lo) {
#if __has_builtin(__builtin_amdgcn_permlane32_swap)
  auto r = __builtin_amdgcn_permlane32_swap(
      __builtin_bit_cast(int, v), __builtin_bit_cast(int, v), false, false);
  return __builtin_bit_cast(float, lo ? (int)r[1] : (int)r[0]);
#else
  return __shfl_xor(v, 32);
#endif
}

// One LSTM block step. Uses kernel-scope wx/wh/biasv/rw0v/rw1v, state
// c0/c1/hv0/hv1, bools re_/lo_. rinv prefolded into the B pack; x-MFMA
// chained with C = h-MFMA result (which carries bias as its C).
#define BLK_STEP(XT0, XT1) do {                                            \
    float _ss = dot44_((XT0), (XT1), (XT1), (XT0));                        \
    _ss = dot44_((XT0), (XT0), (XT1), (XT1));                              \
    _ss += psw16_(_ss, re_);                                               \
    _ss += psw32_(_ss, lo_);                                               \
    const float _rinv = rsq_(_ss * (1.0f / 32.0f) + EPS_);                 \
    const h8 _bh = pk8_(hv0, hv1);                                         \
    f4 _ah0 = mfma_(wh[0], _bh, biasv[0]);                                 \
    f4 _ah1 = mfma_(wh[1], _bh, biasv[1]);                                 \
    f4 _ah2 = mfma_(wh[2], _bh, biasv[2]);                                 \
    f4 _ah3 = mfma_(wh[3], _bh, biasv[3]);                                 \
    f4 _ah4 = mfma_(wh[4], _bh, biasv[4]);                                 \
    f4 _ah5 = mfma_(wh[5], _bh, biasv[5]);                                 \
    f4 _ah6 = mfma_(wh[6], _bh, biasv[6]);                                 \
    f4 _ah7 = mfma_(wh[7], _bh, biasv[7]);                                 \
    const f4 _rs0 = rw0v * _rinv, _rs1 = rw1v * _rinv;                     \
    const h8 _bx = pk8_((XT0) * _rs0, (XT1) * _rs1);                       \
    const f4 _gi0 = mfma_(wx[0], _bx, _ah0);                               \
    const f4 _gi1 = mfma_(wx[1], _bx, _ah1);                               \
    const f4 _gf0 = mfma_(wx[2], _bx, _ah2);                               \
    const f4 _gf1 = mfma_(wx[3], _bx, _ah3);                               \
    const f4 _gg0 = mfma_(wx[4], _bx, _ah4);                               \
    const f4 _gg1 = mfma_(wx[5], _bx, _ah5);                               \
    const f4 _go0 = mfma_(wx[6], _bx, _ah6);                               \
    const f4 _go1 = mfma_(wx[7], _bx, _ah7);                               \
    const f4 _si0 = sg4_(_gi0), _si1 = sg4_(_gi1);                         \
    const f4 _sf0 = sg4_(_gf0), _sf1 = sg4_(_gf1);                         \
    const f4 _tg0 = th4_(_gg0), _tg1 = th4_(_gg1);                         \
    const f4 _so0 = sg4_(_go0), _so1 = sg4_(_go1);                         \
    c0 = _sf0 * c0 + _si0 * _tg0;                                          \
    c1 = _sf1 * c1 + _si1 * _tg1;                                          \
    hv0 = _so0 * thc4_(c0);                                                \
    hv1 = _so1 * thc4_(c1);                                                \
    (XT0) += hv0;                                                          \
    (XT1) += hv1;                                                          \
  } while (0)

__global__ __launch_bounds__(256, 1) void garch_mfma6_kernel(
    const float* __restrict__ obs, const float* __restrict__ prev,
    const float* __restrict__ W_in, const float* __restrict__ b_in,
    const float* __restrict__ rms_w,
    const float* __restrict__ W_ih, const float* __restrict__ W_hh,
    const float* __restrict__ b_ih, const float* __restrict__ b_hh,
    const float* __restrict__ head_w, const float* __restrict__ head_b,
    float* __restrict__ out) {
  const int tid  = threadIdx.x;
  const int k    = tid >> 6;        // wave role == LSTM block
  const int lane = tid & 63;
  const int g    = lane >> 4;       // k-chunk / row group
  const int b    = lane & 15;       // batch column within tile
  const int bg   = blockIdx.x * 16 + b;
  const bool re_ = ((lane >> 4) & 1) == 0;
  const bool lo_ = (lane < 32);

  // xt handoff: [stage][parity][step][bcol][32 rows + pad]
  __shared__ __align__(16) float xslot[3][2][SUP_][16][36];

  // ---- A-fragments / biases for this wave's block (exp2-prescaled) ----
  h8 wx[8], wh[8];
  f4 biasv[8];
  {
    const size_t wb = (size_t)k * 128 * 32;
#pragma unroll
    for (int mi = 0; mi < 8; ++mi) {
      const float scl = (mi == 4 || mi == 5) ? 2.f * LOG2E_ : LOG2E_;
      const int row = 16 * mi + b;
      const float* px = W_ih + wb + (size_t)row * 32;
      f4 x0 = *(const f4*)(px + 4 * g);
      f4 x1 = *(const f4*)(px + 16 + 4 * g);
      wx[mi] = pk8_(x0 * scl, x1 * scl);
      const float* ph = W_hh + wb + (size_t)row * 32;
      f4 h0v = *(const f4*)(ph + 4 * g);
      f4 h1v = *(const f4*)(ph + 16 + 4 * g);
      wh[mi] = pk8_(h0v * scl, h1v * scl);
      f4 bv;
#pragma unroll
      for (int r = 0; r < 4; ++r) {
        const int gr = k * 128 + 16 * mi + 4 * g + r;
        bv[r] = (b_ih[gr] + b_hh[gr]) * scl;
      }
      biasv[mi] = bv;
    }
  }
  f4 rw0v, rw1v;
#pragma unroll
  for (int r = 0; r < 4; ++r) {
    rw0v[r] = rms_w[k * 32 + 4 * g + r];
    rw1v[r] = rms_w[k * 32 + 16 + 4 * g + r];
  }

  // ---- role-specific constants ----
  h8 winA0 = {}, winA1 = {};
  f4 bin0v = {}, bin1v = {};
  const float* obs_b = nullptr; const float* prev_b = nullptr;
  f4 cin[SUP_] = {}, nin[SUP_] = {};   // per-step inputs (this lane's 4 vals)
  if (k == 0) {
    f4 lo0, lo1; const f4 z = {};
#pragma unroll
    for (int r = 0; r < 4; ++r) {
      const int kk = 4 * g + r;
      lo0[r] = (kk < 7) ? W_in[(size_t)b * 7 + kk] : 0.f;
      lo1[r] = (kk < 7) ? W_in[(size_t)(16 + b) * 7 + kk] : 0.f;
    }
    winA0 = pk8_(lo0, z);
    winA1 = pk8_(lo1, z);
#pragma unroll
    for (int r = 0; r < 4; ++r) {
      bin0v[r] = b_in[4 * g + r];
      bin1v[r] = b_in[16 + 4 * g + r];
    }
    obs_b  = obs  + (size_t)bg * S_ * OBS_;
    prev_b = prev + (size_t)bg * S_ * NINS_;
#pragma unroll
    for (int s = 0; s < SUP_; ++s) {
      const float* o = obs_b + (size_t)s * OBS_;
      if (g == 0)      { cin[s][0] = o[0]; cin[s][1] = o[1]; cin[s][2] = o[2]; cin[s][3] = o[3]; }
      else if (g == 1) { cin[s][0] = o[4]; cin[s][1] = prev_b[2 * s]; cin[s][2] = prev_b[2 * s + 1]; cin[s][3] = 0.f; }
    }
  }
  f4 hw00 = {}, hw01 = {}, hw10 = {}, hw11 = {};
  float hb0 = 0.f, hb1 = 0.f;
  if (k == 3) {
#pragma unroll
    for (int r = 0; r < 4; ++r) {
      hw00[r] = head_w[4 * g + r]      * LOG2E_;
      hw01[r] = head_w[16 + 4 * g + r] * LOG2E_;
      hw10[r] = head_w[32 + 4 * g + r] * LOG2E_;
      hw11[r] = head_w[48 + 4 * g + r] * LOG2E_;
    }
    hb0 = head_b[0] * LOG2E_;
    hb1 = head_b[1] * LOG2E_;
  }

  // block state
  f4 c0 = {}, c1 = {}, hv0 = {}, hv1 = {};

  float* out_y  = out;                                // [2][B][S]
  float* out_hT = out + (size_t)NINS_ * B_ * S_;      // [4][B][H]
  float* out_cT = out_hT + (size_t)NBLK_ * B_ * H_;   // [4][B][H]

  for (int tau = 0; tau < TT_ + NBLK_ - 1; ++tau) {
    __syncthreads();
    const int tt = tau - k;           // wave-uniform super-tick window
    if (tt < 0 || tt >= TT_) continue;
    const int t0 = SUP_ * tt;
    const int wp = tau & 1, rp = (tau + 1) & 1;

    // ---- 1. xt tiles for SUP_ timesteps ----
    f4 x0[SUP_], x1[SUP_];
    if (k == 0) {
      if (tt + 1 < TT_) {             // prefetch next super-tick's inputs
#pragma unroll
        for (int s = 0; s < SUP_; ++s) {
          const int t = t0 + SUP_ + s;
          const float* o = obs_b + (size_t)t * OBS_;
          if (g == 0)      { nin[s][0] = o[0]; nin[s][1] = o[1]; nin[s][2] = o[2]; nin[s][3] = o[3]; }
          else if (g == 1) { nin[s][0] = o[4]; nin[s][1] = prev_b[2 * t]; nin[s][2] = prev_b[2 * t + 1]; nin[s][3] = 0.f; }
        }
      }
      const f4 z = {};
#pragma unroll
      for (int s = 0; s < SUP_; ++s) {
        const h8 binp = pk8_(cin[s], z);   // g>=2 lanes: zeros
        x0[s] = mfma_(winA0, binp, bin0v);
        x1[s] = mfma_(winA1, binp, bin1v);
      }
    } else {
#pragma unroll
      for (int s = 0; s < SUP_; ++s) {
        x0[s] = *(const f4*)&xslot[k - 1][rp][s][b][4 * g];
        x1[s] = *(const f4*)&xslot[k - 1][rp][s][b][16 + 4 * g];
      }
    }

    // ---- 2. SUP_ timesteps of this wave's block ----
#pragma unroll
    for (int s = 0; s < SUP_; ++s) {
      BLK_STEP(x0[s], x1[s]);
    }

    // ---- 3. handoff or head ----
    if (k < 3) {
#pragma unroll
      for (int s = 0; s < SUP_; ++s) {
        *(f4*)&xslot[k][wp][s][b][4 * g]      = x0[s];
        *(f4*)&xslot[k][wp][s][b][16 + 4 * g] = x1[s];
      }
    } else {
      float p0[SUP_], p1[SUP_];
#pragma unroll
      for (int s = 0; s < SUP_; ++s) {
        float a = dot44_(hw00, x0[s], hw01, x1[s]);
        float bq = dot44_(hw10, x0[s], hw11, x1[s]);
        a += psw16_(a, re_); a += psw32_(a, lo_);
        bq += psw16_(bq, re_); bq += psw32_(bq, lo_);
        p0[s] = a + hb0;
        p1[s] = bq + hb1;
      }
      if (lane < 16) {
        f4 v0, v1;
#pragma unroll
        for (int s = 0; s < SUP_; ++s) {
          v0[s] = copysignf(fminf(ex2_(fabsf(p0[s])) - 1.f, 5.f),  p0[s]);
          v1[s] = copysignf(fminf(ex2_(fabsf(p1[s])) - 1.f, 10.f), p1[s]);
        }
        *(f4*)&out_y[(size_t)bg * S_ + t0]                   = v0;
        *(f4*)&out_y[(size_t)B_ * S_ + (size_t)bg * S_ + t0] = v1;
      }
    }

    // ---- 4. final states ----
    if (tt == TT_ - 1) {
      float* hp = out_hT + ((size_t)k * B_ + bg) * H_;
      float* cp = out_cT + ((size_t)k * B_ + bg) * H_;
#pragma unroll
      for (int r = 0; r < 4; ++r) {
        hp[4 * g + r]      = hv0[r];
        hp[16 + 4 * g + r] = hv1[r];
        cp[4 * g + r]      = c0[r];
        cp[16 + 4 * g + r] = c1[r];
      }
    }

    if (k == 0) {
#pragma unroll
      for (int s = 0; s < SUP_; ++s) cin[s] = nin[s];
    }
  }
}

extern "C" void kernel_launch(void* const* d_in, const int* in_sizes, int n_in,
                              void* d_out, int out_size, void* d_ws, size_t ws_size,
                              hipStream_t stream) {
  (void)in_sizes; (void)n_in; (void)d_ws; (void)ws_size; (void)out_size;
  garch_mfma6_kernel<<<dim3(B_ / 16), dim3(256), 0, stream>>>(
      (const float*)d_in[0],  // obs_sequence [B,S,OBS]
      (const float*)d_in[1],  // prev_actions [B,S,NINS]
      (const float*)d_in[2],  // W_in [H, OBS+NINS]
      (const float*)d_in[3],  // b_in [H]
      (const float*)d_in[4],  // rms_w [NBLK,H]
      (const float*)d_in[5],  // W_ih [NBLK,4H,H]
      (const float*)d_in[6],  // W_hh [NBLK,4H,H]
      (const float*)d_in[7],  // b_ih [NBLK,4H]
      (const float*)d_in[8],  // b_hh [NBLK,4H]
      (const float*)d_in[9],  // head_w [NINS,H]
      (const float*)d_in[10], // head_b [NINS]
      (float*)d_out);
}

// Round 17
// 429.387 us; speedup vs baseline: 2.4490x; 1.0848x over previous
//
#include <hip/hip_runtime.h>

// PolicyNetGARCH: B=1024 S=512 OBS=5 NINS=2 H=32 NBLK=4
// Round 17: R16 structure (64 WGs x 4 stage-waves, wave k = LSTM block k,
// SUP=4 super-tick, skewed pipeline, parity-dbuf LDS handoff, permlane
// reduces, exp2-prescaled gates, verified C/D==B-fragment feedback) with
// the step loop re-planned around the serial h-chain:
//  (1) ALL x-side work hoisted per super-tick: 4 RMS reduces + 4 rinv-folded
//      bx packs + 32 x-MFMAs (gx[s][m] = Wx@xn + bias, bias as C). These
//      depend only on slot data -> pipeline freely; the serial loop is just
//      pack(bh) -> 8 h-MFMA (C=gx) -> activations -> state.
//  (2) fused activations: si*tg = (1-Eg)*rcp((1+Ei)(1+Eg)),
//      so*tanh(c) = (1-Ec)*rcp((1+Eo)(1+Ec)) -> 64 trans/step vs 80.

constexpr int B_ = 1024, S_ = 512, OBS_ = 5, NINS_ = 2, H_ = 32, NBLK_ = 4;
constexpr int SUP_ = 4;           // timesteps per super-tick
constexpr int TT_ = S_ / SUP_;    // super-ticks = 128
constexpr float EPS_ = 1e-6f;
constexpr float LOG2E_ = 1.4426950408889634f;

typedef __fp16 h2 __attribute__((ext_vector_type(2)));
typedef __fp16 h8 __attribute__((ext_vector_type(8)));
typedef float  f4 __attribute__((ext_vector_type(4)));
typedef int    i4 __attribute__((ext_vector_type(4)));

__device__ __forceinline__ float rcp_(float x) { return __builtin_amdgcn_rcpf(x); }
__device__ __forceinline__ float rsq_(float x) { return __builtin_amdgcn_rsqf(x); }
__device__ __forceinline__ float ex2_(float x) { return __builtin_amdgcn_exp2f(x); }
__device__ __forceinline__ h2 pk_(float a, float b) {
  return __builtin_amdgcn_cvt_pkrtz(a, b);
}
__device__ __forceinline__ h8 pk8_(f4 lo, f4 hi) {
  i4 q;
  q[0] = __builtin_bit_cast(int, pk_(lo[0], lo[1]));
  q[1] = __builtin_bit_cast(int, pk_(lo[2], lo[3]));
  q[2] = __builtin_bit_cast(int, pk_(hi[0], hi[1]));
  q[3] = __builtin_bit_cast(int, pk_(hi[2], hi[3]));
  return __builtin_bit_cast(h8, q);
}
__device__ __forceinline__ f4 mfma_(h8 a, h8 b, f4 c) {
  return __builtin_amdgcn_mfma_f32_16x16x32_f16(a, b, c, 0, 0, 0);
}
__device__ __forceinline__ f4 e4n_(f4 a) {          // ex2(-a) elementwise
  f4 r;
  r[0] = ex2_(-a[0]); r[1] = ex2_(-a[1]);
  r[2] = ex2_(-a[2]); r[3] = ex2_(-a[3]);
  return r;
}
__device__ __forceinline__ f4 rcp4_(f4 a) {
  f4 r;
  r[0] = rcp_(a[0]); r[1] = rcp_(a[1]);
  r[2] = rcp_(a[2]); r[3] = rcp_(a[3]);
  return r;
}
__device__ __forceinline__ float dot44_(f4 a, f4 x, f4 b2, f4 y) {
  float s = a[0] * x[0];
  s = fmaf(a[1], x[1], s); s = fmaf(a[2], x[2], s); s = fmaf(a[3], x[3], s);
  s = fmaf(b2[0], y[0], s); s = fmaf(b2[1], y[1], s);
  s = fmaf(b2[2], y[2], s); s = fmaf(b2[3], y[3], s);
  return s;
}
// partner across lane^16 (VALU permlane; re = even 16-row)
__device__ __forceinline__ float psw16_(float v, bool re) {
#if __has_builtin(__builtin_amdgcn_permlane16_swap)
  auto r = __builtin_amdgcn_permlane16_swap(
      __builtin_bit_cast(int, v), __builtin_bit_cast(int, v), false, false);
  return __builtin_bit_cast(float, re ? (int)r[1] : (int)r[0]);
#else
  return __shfl_xor(v, 16);
#endif
}
// partner across lane^32 (VALU permlane; lo = lane<32)
__device__ __forceinline__ float psw32_(float v, bool lo) {
#if __has_builtin(__builtin_amdgcn_permlane32_swap)
  auto r = __builtin_amdgcn_permlane32_swap(
      __builtin_bit_cast(int, v), __builtin_bit_cast(int, v), false, false);
  return __builtin_bit_cast(float, lo ? (int)r[1] : (int)r[0]);
#else
  return __shfl_xor(v, 32);
#endif
}

// Fused activations for one tile: updates C and HV.
// si*tg = (1-Eg)*rcp((1+Ei)(1+Eg)); sf = rcp(1+Ef);
// h = so*tanh(c) = (1-Ec)*rcp((1+Eo)(1+Ec)).
#define ACT_TILE(GI, GF, GG, GO, C, HV) do {                               \
    const f4 _one = {1.f, 1.f, 1.f, 1.f};                                  \
    const f4 _Ei = e4n_(GI);                                               \
    const f4 _Eg = e4n_(GG);                                               \
    const f4 _Ef = e4n_(GF);                                               \
    const f4 _sitg = (_one - _Eg) * rcp4_((_one + _Ei) * (_one + _Eg));    \
    const f4 _sf = rcp4_(_one + _Ef);                                      \
    (C) = _sf * (C) + _sitg;                                               \
    const f4 _Eo = e4n_(GO);                                               \
    const f4 _Ec = e4n_((C) * (2.f * LOG2E_));                             \
    (HV) = (_one - _Ec) * rcp4_((_one + _Eo) * (_one + _Ec));              \
  } while (0)

__global__ __launch_bounds__(256, 1) void garch_mfma7_kernel(
    const float* __restrict__ obs, const float* __restrict__ prev,
    const float* __restrict__ W_in, const float* __restrict__ b_in,
    const float* __restrict__ rms_w,
    const float* __restrict__ W_ih, const float* __restrict__ W_hh,
    const float* __restrict__ b_ih, const float* __restrict__ b_hh,
    const float* __restrict__ head_w, const float* __restrict__ head_b,
    float* __restrict__ out) {
  const int tid  = threadIdx.x;
  const int k    = tid >> 6;        // wave role == LSTM block
  const int lane = tid & 63;
  const int g    = lane >> 4;       // k-chunk / row group
  const int b    = lane & 15;       // batch column within tile
  const int bg   = blockIdx.x * 16 + b;
  const bool re_ = ((lane >> 4) & 1) == 0;
  const bool lo_ = (lane < 32);

  // xt handoff: [stage][parity][step][bcol][32 rows + pad]
  __shared__ __align__(16) float xslot[3][2][SUP_][16][36];

  // ---- A-fragments / biases for this wave's block (exp2-prescaled) ----
  h8 wx[8], wh[8];
  f4 biasv[8];
  {
    const size_t wb = (size_t)k * 128 * 32;
#pragma unroll
    for (int mi = 0; mi < 8; ++mi) {
      const float scl = (mi == 4 || mi == 5) ? 2.f * LOG2E_ : LOG2E_;
      const int row = 16 * mi + b;
      const float* px = W_ih + wb + (size_t)row * 32;
      f4 x0 = *(const f4*)(px + 4 * g);
      f4 x1 = *(const f4*)(px + 16 + 4 * g);
      wx[mi] = pk8_(x0 * scl, x1 * scl);
      const float* ph = W_hh + wb + (size_t)row * 32;
      f4 h0v = *(const f4*)(ph + 4 * g);
      f4 h1v = *(const f4*)(ph + 16 + 4 * g);
      wh[mi] = pk8_(h0v * scl, h1v * scl);
      f4 bv;
#pragma unroll
      for (int r = 0; r < 4; ++r) {
        const int gr = k * 128 + 16 * mi + 4 * g + r;
        bv[r] = (b_ih[gr] + b_hh[gr]) * scl;
      }
      biasv[mi] = bv;
    }
  }
  f4 rw0v, rw1v;
#pragma unroll
  for (int r = 0; r < 4; ++r) {
    rw0v[r] = rms_w[k * 32 + 4 * g + r];
    rw1v[r] = rms_w[k * 32 + 16 + 4 * g + r];
  }

  // ---- role-specific constants ----
  h8 winA0 = {}, winA1 = {};
  f4 bin0v = {}, bin1v = {};
  const float* obs_b = nullptr; const float* prev_b = nullptr;
  f4 cin[SUP_] = {}, nin[SUP_] = {};   // per-step inputs (this lane's 4 vals)
  if (k == 0) {
    f4 lo0, lo1; const f4 z = {};
#pragma unroll
    for (int r = 0; r < 4; ++r) {
      const int kk = 4 * g + r;
      lo0[r] = (kk < 7) ? W_in[(size_t)b * 7 + kk] : 0.f;
      lo1[r] = (kk < 7) ? W_in[(size_t)(16 + b) * 7 + kk] : 0.f;
    }
    winA0 = pk8_(lo0, z);
    winA1 = pk8_(lo1, z);
#pragma unroll
    for (int r = 0; r < 4; ++r) {
      bin0v[r] = b_in[4 * g + r];
      bin1v[r] = b_in[16 + 4 * g + r];
    }
    obs_b  = obs  + (size_t)bg * S_ * OBS_;
    prev_b = prev + (size_t)bg * S_ * NINS_;
#pragma unroll
    for (int s = 0; s < SUP_; ++s) {
      const float* o = obs_b + (size_t)s * OBS_;
      if (g == 0)      { cin[s][0] = o[0]; cin[s][1] = o[1]; cin[s][2] = o[2]; cin[s][3] = o[3]; }
      else if (g == 1) { cin[s][0] = o[4]; cin[s][1] = prev_b[2 * s]; cin[s][2] = prev_b[2 * s + 1]; cin[s][3] = 0.f; }
    }
  }
  f4 hw00 = {}, hw01 = {}, hw10 = {}, hw11 = {};
  float hb0 = 0.f, hb1 = 0.f;
  if (k == 3) {
#pragma unroll
    for (int r = 0; r < 4; ++r) {
      hw00[r] = head_w[4 * g + r]      * LOG2E_;
      hw01[r] = head_w[16 + 4 * g + r] * LOG2E_;
      hw10[r] = head_w[32 + 4 * g + r] * LOG2E_;
      hw11[r] = head_w[48 + 4 * g + r] * LOG2E_;
    }
    hb0 = head_b[0] * LOG2E_;
    hb1 = head_b[1] * LOG2E_;
  }

  // block state
  f4 c0 = {}, c1 = {}, hv0 = {}, hv1 = {};

  float* out_y  = out;                                // [2][B][S]
  float* out_hT = out + (size_t)NINS_ * B_ * S_;      // [4][B][H]
  float* out_cT = out_hT + (size_t)NBLK_ * B_ * H_;   // [4][B][H]

  for (int tau = 0; tau < TT_ + NBLK_ - 1; ++tau) {
    __syncthreads();
    const int tt = tau - k;           // wave-uniform super-tick window
    if (tt < 0 || tt >= TT_) continue;
    const int t0 = SUP_ * tt;
    const int wp = tau & 1, rp = (tau + 1) & 1;

    // ---- 1. xt tiles for SUP_ timesteps ----
    f4 x0[SUP_], x1[SUP_];
    if (k == 0) {
      if (tt + 1 < TT_) {             // prefetch next super-tick's inputs
#pragma unroll
        for (int s = 0; s < SUP_; ++s) {
          const int t = t0 + SUP_ + s;
          const float* o = obs_b + (size_t)t * OBS_;
          if (g == 0)      { nin[s][0] = o[0]; nin[s][1] = o[1]; nin[s][2] = o[2]; nin[s][3] = o[3]; }
          else if (g == 1) { nin[s][0] = o[4]; nin[s][1] = prev_b[2 * t]; nin[s][2] = prev_b[2 * t + 1]; nin[s][3] = 0.f; }
        }
      }
      const f4 z = {};
#pragma unroll
      for (int s = 0; s < SUP_; ++s) {
        const h8 binp = pk8_(cin[s], z);   // g>=2 lanes: zeros
        x0[s] = mfma_(winA0, binp, bin0v);
        x1[s] = mfma_(winA1, binp, bin1v);
      }
    } else {
#pragma unroll
      for (int s = 0; s < SUP_; ++s) {
        x0[s] = *(const f4*)&xslot[k - 1][rp][s][b][4 * g];
        x1[s] = *(const f4*)&xslot[k - 1][rp][s][b][16 + 4 * g];
      }
    }

    // ---- 2a. HOISTED x-side: reduces + packs + 32 x-MFMAs ----
    h8 bx[SUP_];
#pragma unroll
    for (int s = 0; s < SUP_; ++s) {
      float ss = dot44_(x0[s], x0[s], x1[s], x1[s]);
      ss += psw16_(ss, re_);
      ss += psw32_(ss, lo_);
      const float rinv = rsq_(ss * (1.0f / 32.0f) + EPS_);
      bx[s] = pk8_(x0[s] * (rw0v * rinv), x1[s] * (rw1v * rinv));
    }
    f4 gx[SUP_][8];
#pragma unroll
    for (int s = 0; s < SUP_; ++s) {
#pragma unroll
      for (int m = 0; m < 8; ++m) {
        gx[s][m] = mfma_(wx[m], bx[s], biasv[m]);
      }
    }

    // ---- 2b. serial h-chain: pack(bh) -> 8 h-MFMA -> activations ----
#pragma unroll
    for (int s = 0; s < SUP_; ++s) {
      const h8 bh = pk8_(hv0, hv1);
      const f4 gi0 = mfma_(wh[0], bh, gx[s][0]);
      const f4 gi1 = mfma_(wh[1], bh, gx[s][1]);
      const f4 gf0 = mfma_(wh[2], bh, gx[s][2]);
      const f4 gf1 = mfma_(wh[3], bh, gx[s][3]);
      const f4 gg0 = mfma_(wh[4], bh, gx[s][4]);
      const f4 gg1 = mfma_(wh[5], bh, gx[s][5]);
      const f4 go0 = mfma_(wh[6], bh, gx[s][6]);
      const f4 go1 = mfma_(wh[7], bh, gx[s][7]);
      ACT_TILE(gi0, gf0, gg0, go0, c0, hv0);
      ACT_TILE(gi1, gf1, gg1, go1, c1, hv1);
      x0[s] += hv0;
      x1[s] += hv1;
    }

    // ---- 3. handoff or head ----
    if (k < 3) {
#pragma unroll
      for (int s = 0; s < SUP_; ++s) {
        *(f4*)&xslot[k][wp][s][b][4 * g]      = x0[s];
        *(f4*)&xslot[k][wp][s][b][16 + 4 * g] = x1[s];
      }
    } else {
      float p0[SUP_], p1[SUP_];
#pragma unroll
      for (int s = 0; s < SUP_; ++s) {
        float a = dot44_(hw00, x0[s], hw01, x1[s]);
        float bq = dot44_(hw10, x0[s], hw11, x1[s]);
        a += psw16_(a, re_); a += psw32_(a, lo_);
        bq += psw16_(bq, re_); bq += psw32_(bq, lo_);
        p0[s] = a + hb0;
        p1[s] = bq + hb1;
      }
      if (lane < 16) {
        f4 v0, v1;
#pragma unroll
        for (int s = 0; s < SUP_; ++s) {
          v0[s] = copysignf(fminf(ex2_(fabsf(p0[s])) - 1.f, 5.f),  p0[s]);
          v1[s] = copysignf(fminf(ex2_(fabsf(p1[s])) - 1.f, 10.f), p1[s]);
        }
        *(f4*)&out_y[(size_t)bg * S_ + t0]                   = v0;
        *(f4*)&out_y[(size_t)B_ * S_ + (size_t)bg * S_ + t0] = v1;
      }
    }

    // ---- 4. final states ----
    if (tt == TT_ - 1) {
      float* hp = out_hT + ((size_t)k * B_ + bg) * H_;
      float* cp = out_cT + ((size_t)k * B_ + bg) * H_;
#pragma unroll
      for (int r = 0; r < 4; ++r) {
        hp[4 * g + r]      = hv0[r];
        hp[16 + 4 * g + r] = hv1[r];
        cp[4 * g + r]      = c0[r];
        cp[16 + 4 * g + r] = c1[r];
      }
    }

    if (k == 0) {
#pragma unroll
      for (int s = 0; s < SUP_; ++s) cin[s] = nin[s];
    }
  }
}

extern "C" void kernel_launch(void* const* d_in, const int* in_sizes, int n_in,
                              void* d_out, int out_size, void* d_ws, size_t ws_size,
                              hipStream_t stream) {
  (void)in_sizes; (void)n_in; (void)d_ws; (void)ws_size; (void)out_size;
  garch_mfma7_kernel<<<dim3(B_ / 16), dim3(256), 0, stream>>>(
      (const float*)d_in[0],  // obs_sequence [B,S,OBS]
      (const float*)d_in[1],  // prev_actions [B,S,NINS]
      (const float*)d_in[2],  // W_in [H, OBS+NINS]
      (const float*)d_in[3],  // b_in [H]
      (const float*)d_in[4],  // rms_w [NBLK,H]
      (const float*)d_in[5],  // W_ih [NBLK,4H,H]
      (const float*)d_in[6],  // W_hh [NBLK,4H,H]
      (const float*)d_in[7],  // b_ih [NBLK,4H]
      (const float*)d_in[8],  // b_hh [NBLK,4H]
      (const float*)d_in[9],  // head_w [NINS,H]
      (const float*)d_in[10], // head_b [NINS]
      (float*)d_out);
}

// Round 18
// 424.457 us; speedup vs baseline: 2.4775x; 1.0116x over previous
//
#include <hip/hip_runtime.h>

// PolicyNetGARCH: B=1024 S=512 OBS=5 NINS=2 H=32 NBLK=4
// Round 18: R17 (64 WGs x 4 stage-waves, wave k = block k, skewed pipeline,
// parity-dbuf LDS handoff, permlane reduces, hoisted x-side, fused
// exp2-domain activations, verified C/D==B-fragment feedback) with:
//  (1) SUP=8 timesteps per barrier (131 -> 67 barriers), processed as TWO
//      phases of 4 steps so the register live-set stays at R17's level
//      (gx[4][8] + x[4] tiles per phase, not 8),
//  (2) k==0 input prefetch double-buffer removed: cin[s] reloaded right
//      after consumption (latency hides under the rest of the phase),
//  (3) single-rcp gate fusion: r=rcp((1+Ei)(1+Eg)(1+Ef)),
//      sitg=(1-Eg)(1+Ef)r, sf=(1+Ei)(1+Eg)r -> 28 trans/tile vs 32.
// LDS = 110592 B (gfx950 allows 160KB/WG).

constexpr int B_ = 1024, S_ = 512, OBS_ = 5, NINS_ = 2, H_ = 32, NBLK_ = 4;
constexpr int SUP_ = 8;           // timesteps per barrier
constexpr int PH_  = 4;           // steps per phase (2 phases per barrier)
constexpr int TT_ = S_ / SUP_;    // super-ticks = 64
constexpr float EPS_ = 1e-6f;
constexpr float LOG2E_ = 1.4426950408889634f;

typedef __fp16 h2 __attribute__((ext_vector_type(2)));
typedef __fp16 h8 __attribute__((ext_vector_type(8)));
typedef float  f4 __attribute__((ext_vector_type(4)));
typedef int    i4 __attribute__((ext_vector_type(4)));

__device__ __forceinline__ float rcp_(float x) { return __builtin_amdgcn_rcpf(x); }
__device__ __forceinline__ float rsq_(float x) { return __builtin_amdgcn_rsqf(x); }
__device__ __forceinline__ float ex2_(float x) { return __builtin_amdgcn_exp2f(x); }
__device__ __forceinline__ h2 pk_(float a, float b) {
  return __builtin_amdgcn_cvt_pkrtz(a, b);
}
__device__ __forceinline__ h8 pk8_(f4 lo, f4 hi) {
  i4 q;
  q[0] = __builtin_bit_cast(int, pk_(lo[0], lo[1]));
  q[1] = __builtin_bit_cast(int, pk_(lo[2], lo[3]));
  q[2] = __builtin_bit_cast(int, pk_(hi[0], hi[1]));
  q[3] = __builtin_bit_cast(int, pk_(hi[2], hi[3]));
  return __builtin_bit_cast(h8, q);
}
__device__ __forceinline__ f4 mfma_(h8 a, h8 b, f4 c) {
  return __builtin_amdgcn_mfma_f32_16x16x32_f16(a, b, c, 0, 0, 0);
}
__device__ __forceinline__ f4 e4n_(f4 a) {          // ex2(-a) elementwise
  f4 r;
  r[0] = ex2_(-a[0]); r[1] = ex2_(-a[1]);
  r[2] = ex2_(-a[2]); r[3] = ex2_(-a[3]);
  return r;
}
__device__ __forceinline__ f4 rcp4_(f4 a) {
  f4 r;
  r[0] = rcp_(a[0]); r[1] = rcp_(a[1]);
  r[2] = rcp_(a[2]); r[3] = rcp_(a[3]);
  return r;
}
__device__ __forceinline__ float dot44_(f4 a, f4 x, f4 b2, f4 y) {
  float s = a[0] * x[0];
  s = fmaf(a[1], x[1], s); s = fmaf(a[2], x[2], s); s = fmaf(a[3], x[3], s);
  s = fmaf(b2[0], y[0], s); s = fmaf(b2[1], y[1], s);
  s = fmaf(b2[2], y[2], s); s = fmaf(b2[3], y[3], s);
  return s;
}
// partner across lane^16 (VALU permlane; re = even 16-row)
__device__ __forceinline__ float psw16_(float v, bool re) {
#if __has_builtin(__builtin_amdgcn_permlane16_swap)
  auto r = __builtin_amdgcn_permlane16_swap(
      __builtin_bit_cast(int, v), __builtin_bit_cast(int, v), false, false);
  return __builtin_bit_cast(float, re ? (int)r[1] : (int)r[0]);
#else
  return __shfl_xor(v, 16);
#endif
}
// partner across lane^32 (VALU permlane; lo = lane<32)
__device__ __forceinline__ float psw32_(float v, bool lo) {
#if __has_builtin(__builtin_amdgcn_permlane32_swap)
  auto r = __builtin_amdgcn_permlane32_swap(
      __builtin_bit_cast(int, v), __builtin_bit_cast(int, v), false, false);
  return __builtin_bit_cast(float, lo ? (int)r[1] : (int)r[0]);
#else
  return __shfl_xor(v, 32);
#endif
}

// Fused activations (single-rcp gate path): updates C and HV.
// sitg=(1-Eg)(1+Ef)r, sf=(1+Ei)(1+Eg)r with r=rcp((1+Ei)(1+Eg)(1+Ef));
// h=(1-Ec)*rcp((1+Eo)(1+Ec)).
#define ACT_TILE(GI, GF, GG, GO, C, HV) do {                               \
    const f4 _one = {1.f, 1.f, 1.f, 1.f};                                  \
    const f4 _Ei = e4n_(GI);                                               \
    const f4 _Eg = e4n_(GG);                                               \
    const f4 _Ef = e4n_(GF);                                               \
    const f4 _a = (_one + _Ei) * (_one + _Eg);                             \
    const f4 _f = _one + _Ef;                                              \
    const f4 _r = rcp4_(_a * _f);                                          \
    const f4 _sitg = (_one - _Eg) * _f * _r;                               \
    const f4 _sf = _a * _r;                                                \
    (C) = _sf * (C) + _sitg;                                               \
    const f4 _Eo = e4n_(GO);                                               \
    const f4 _Ec = e4n_((C) * (2.f * LOG2E_));                             \
    (HV) = (_one - _Ec) * rcp4_((_one + _Eo) * (_one + _Ec));              \
  } while (0)

__global__ __launch_bounds__(256, 1) void garch_mfma8_kernel(
    const float* __restrict__ obs, const float* __restrict__ prev,
    const float* __restrict__ W_in, const float* __restrict__ b_in,
    const float* __restrict__ rms_w,
    const float* __restrict__ W_ih, const float* __restrict__ W_hh,
    const float* __restrict__ b_ih, const float* __restrict__ b_hh,
    const float* __restrict__ head_w, const float* __restrict__ head_b,
    float* __restrict__ out) {
  const int tid  = threadIdx.x;
  const int k    = tid >> 6;        // wave role == LSTM block
  const int lane = tid & 63;
  const int g    = lane >> 4;       // k-chunk / row group
  const int b    = lane & 15;       // batch column within tile
  const int bg   = blockIdx.x * 16 + b;
  const bool re_ = ((lane >> 4) & 1) == 0;
  const bool lo_ = (lane < 32);

  // xt handoff: [stage][parity][step][bcol][32 rows + pad] = 110592 B
  __shared__ __align__(16) float xslot[3][2][SUP_][16][36];

  // ---- A-fragments / biases for this wave's block (exp2-prescaled) ----
  h8 wx[8], wh[8];
  f4 biasv[8];
  {
    const size_t wb = (size_t)k * 128 * 32;
#pragma unroll
    for (int mi = 0; mi < 8; ++mi) {
      const float scl = (mi == 4 || mi == 5) ? 2.f * LOG2E_ : LOG2E_;
      const int row = 16 * mi + b;
      const float* px = W_ih + wb + (size_t)row * 32;
      f4 x0 = *(const f4*)(px + 4 * g);
      f4 x1 = *(const f4*)(px + 16 + 4 * g);
      wx[mi] = pk8_(x0 * scl, x1 * scl);
      const float* ph = W_hh + wb + (size_t)row * 32;
      f4 h0v = *(const f4*)(ph + 4 * g);
      f4 h1v = *(const f4*)(ph + 16 + 4 * g);
      wh[mi] = pk8_(h0v * scl, h1v * scl);
      f4 bv;
#pragma unroll
      for (int r = 0; r < 4; ++r) {
        const int gr = k * 128 + 16 * mi + 4 * g + r;
        bv[r] = (b_ih[gr] + b_hh[gr]) * scl;
      }
      biasv[mi] = bv;
    }
  }
  f4 rw0v, rw1v;
#pragma unroll
  for (int r = 0; r < 4; ++r) {
    rw0v[r] = rms_w[k * 32 + 4 * g + r];
    rw1v[r] = rms_w[k * 32 + 16 + 4 * g + r];
  }

  // ---- role-specific constants ----
  h8 winA0 = {}, winA1 = {};
  f4 bin0v = {}, bin1v = {};
  const float* obs_b = nullptr; const float* prev_b = nullptr;
  f4 cin[SUP_] = {};                // per-step inputs (this lane's 4 vals)
  if (k == 0) {
    f4 lo0, lo1; const f4 z = {};
#pragma unroll
    for (int r = 0; r < 4; ++r) {
      const int kk = 4 * g + r;
      lo0[r] = (kk < 7) ? W_in[(size_t)b * 7 + kk] : 0.f;
      lo1[r] = (kk < 7) ? W_in[(size_t)(16 + b) * 7 + kk] : 0.f;
    }
    winA0 = pk8_(lo0, z);
    winA1 = pk8_(lo1, z);
#pragma unroll
    for (int r = 0; r < 4; ++r) {
      bin0v[r] = b_in[4 * g + r];
      bin1v[r] = b_in[16 + 4 * g + r];
    }
    obs_b  = obs  + (size_t)bg * S_ * OBS_;
    prev_b = prev + (size_t)bg * S_ * NINS_;
#pragma unroll
    for (int s = 0; s < SUP_; ++s) {
      const float* o = obs_b + (size_t)s * OBS_;
      if (g == 0)      { cin[s][0] = o[0]; cin[s][1] = o[1]; cin[s][2] = o[2]; cin[s][3] = o[3]; }
      else if (g == 1) { cin[s][0] = o[4]; cin[s][1] = prev_b[2 * s]; cin[s][2] = prev_b[2 * s + 1]; cin[s][3] = 0.f; }
    }
  }
  f4 hw00 = {}, hw01 = {}, hw10 = {}, hw11 = {};
  float hb0 = 0.f, hb1 = 0.f;
  if (k == 3) {
#pragma unroll
    for (int r = 0; r < 4; ++r) {
      hw00[r] = head_w[4 * g + r]      * LOG2E_;
      hw01[r] = head_w[16 + 4 * g + r] * LOG2E_;
      hw10[r] = head_w[32 + 4 * g + r] * LOG2E_;
      hw11[r] = head_w[48 + 4 * g + r] * LOG2E_;
    }
    hb0 = head_b[0] * LOG2E_;
    hb1 = head_b[1] * LOG2E_;
  }

  // block state
  f4 c0 = {}, c1 = {}, hv0 = {}, hv1 = {};

  float* out_y  = out;                                // [2][B][S]
  float* out_hT = out + (size_t)NINS_ * B_ * S_;      // [4][B][H]
  float* out_cT = out_hT + (size_t)NBLK_ * B_ * H_;   // [4][B][H]

  for (int tau = 0; tau < TT_ + NBLK_ - 1; ++tau) {
    __syncthreads();
    const int tt = tau - k;           // wave-uniform super-tick window
    if (tt < 0 || tt >= TT_) continue;
    const int t0 = SUP_ * tt;
    const int wp = tau & 1, rp = (tau + 1) & 1;

#pragma unroll
    for (int p = 0; p < SUP_ / PH_; ++p) {
      // ---- 1. xt tiles for this phase's PH_ timesteps ----
      f4 x0[PH_], x1[PH_];
      if (k == 0) {
        const f4 z = {};
#pragma unroll
        for (int s = 0; s < PH_; ++s) {
          const int sg_ = p * PH_ + s;
          const h8 binp = pk8_(cin[sg_], z);   // g>=2 lanes: zeros
          x0[s] = mfma_(winA0, binp, bin0v);
          x1[s] = mfma_(winA1, binp, bin1v);
        }
        if (tt + 1 < TT_) {           // reload consumed inputs (next super-tick)
#pragma unroll
          for (int s = 0; s < PH_; ++s) {
            const int sg_ = p * PH_ + s;
            const int t = t0 + SUP_ + sg_;
            const float* o = obs_b + (size_t)t * OBS_;
            if (g == 0)      { cin[sg_][0] = o[0]; cin[sg_][1] = o[1]; cin[sg_][2] = o[2]; cin[sg_][3] = o[3]; }
            else if (g == 1) { cin[sg_][0] = o[4]; cin[sg_][1] = prev_b[2 * t]; cin[sg_][2] = prev_b[2 * t + 1]; cin[sg_][3] = 0.f; }
          }
        }
      } else {
#pragma unroll
        for (int s = 0; s < PH_; ++s) {
          const int sg_ = p * PH_ + s;
          x0[s] = *(const f4*)&xslot[k - 1][rp][sg_][b][4 * g];
          x1[s] = *(const f4*)&xslot[k - 1][rp][sg_][b][16 + 4 * g];
        }
      }

      // ---- 2a. HOISTED x-side: reduces + packs + 32 x-MFMAs ----
      h8 bx[PH_];
#pragma unroll
      for (int s = 0; s < PH_; ++s) {
        float ss = dot44_(x0[s], x0[s], x1[s], x1[s]);
        ss += psw16_(ss, re_);
        ss += psw32_(ss, lo_);
        const float rinv = rsq_(ss * (1.0f / 32.0f) + EPS_);
        bx[s] = pk8_(x0[s] * (rw0v * rinv), x1[s] * (rw1v * rinv));
      }
      f4 gx[PH_][8];
#pragma unroll
      for (int s = 0; s < PH_; ++s) {
#pragma unroll
        for (int m = 0; m < 8; ++m) {
          gx[s][m] = mfma_(wx[m], bx[s], biasv[m]);
        }
      }

      // ---- 2b. serial h-chain ----
#pragma unroll
      for (int s = 0; s < PH_; ++s) {
        const h8 bh = pk8_(hv0, hv1);
        const f4 gi0 = mfma_(wh[0], bh, gx[s][0]);
        const f4 gi1 = mfma_(wh[1], bh, gx[s][1]);
        const f4 gf0 = mfma_(wh[2], bh, gx[s][2]);
        const f4 gf1 = mfma_(wh[3], bh, gx[s][3]);
        const f4 gg0 = mfma_(wh[4], bh, gx[s][4]);
        const f4 gg1 = mfma_(wh[5], bh, gx[s][5]);
        const f4 go0 = mfma_(wh[6], bh, gx[s][6]);
        const f4 go1 = mfma_(wh[7], bh, gx[s][7]);
        ACT_TILE(gi0, gf0, gg0, go0, c0, hv0);
        ACT_TILE(gi1, gf1, gg1, go1, c1, hv1);
        x0[s] += hv0;
        x1[s] += hv1;
      }

      // ---- 3. handoff or head for this phase ----
      if (k < 3) {
#pragma unroll
        for (int s = 0; s < PH_; ++s) {
          const int sg_ = p * PH_ + s;
          *(f4*)&xslot[k][wp][sg_][b][4 * g]      = x0[s];
          *(f4*)&xslot[k][wp][sg_][b][16 + 4 * g] = x1[s];
        }
      } else {
        float p0[PH_], p1[PH_];
#pragma unroll
        for (int s = 0; s < PH_; ++s) {
          float a = dot44_(hw00, x0[s], hw01, x1[s]);
          float bq = dot44_(hw10, x0[s], hw11, x1[s]);
          a += psw16_(a, re_); a += psw32_(a, lo_);
          bq += psw16_(bq, re_); bq += psw32_(bq, lo_);
          p0[s] = a + hb0;
          p1[s] = bq + hb1;
        }
        if (lane < 16) {
          f4 v0, v1;
#pragma unroll
          for (int s = 0; s < PH_; ++s) {
            v0[s] = copysignf(fminf(ex2_(fabsf(p0[s])) - 1.f, 5.f),  p0[s]);
            v1[s] = copysignf(fminf(ex2_(fabsf(p1[s])) - 1.f, 10.f), p1[s]);
          }
          *(f4*)&out_y[(size_t)bg * S_ + t0 + p * PH_]                   = v0;
          *(f4*)&out_y[(size_t)B_ * S_ + (size_t)bg * S_ + t0 + p * PH_] = v1;
        }
      }
    }

    // ---- 4. final states ----
    if (tt == TT_ - 1) {
      float* hp = out_hT + ((size_t)k * B_ + bg) * H_;
      float* cp = out_cT + ((size_t)k * B_ + bg) * H_;
#pragma unroll
      for (int r = 0; r < 4; ++r) {
        hp[4 * g + r]      = hv0[r];
        hp[16 + 4 * g + r] = hv1[r];
        cp[4 * g + r]      = c0[r];
        cp[16 + 4 * g + r] = c1[r];
      }
    }
  }
}

extern "C" void kernel_launch(void* const* d_in, const int* in_sizes, int n_in,
                              void* d_out, int out_size, void* d_ws, size_t ws_size,
                              hipStream_t stream) {
  (void)in_sizes; (void)n_in; (void)d_ws; (void)ws_size; (void)out_size;
  garch_mfma8_kernel<<<dim3(B_ / 16), dim3(256), 0, stream>>>(
      (const float*)d_in[0],  // obs_sequence [B,S,OBS]
      (const float*)d_in[1],  // prev_actions [B,S,NINS]
      (const float*)d_in[2],  // W_in [H, OBS+NINS]
      (const float*)d_in[3],  // b_in [H]
      (const float*)d_in[4],  // rms_w [NBLK,H]
      (const float*)d_in[5],  // W_ih [NBLK,4H,H]
      (const float*)d_in[6],  // W_hh [NBLK,4H,H]
      (const float*)d_in[7],  // b_ih [NBLK,4H]
      (const float*)d_in[8],  // b_hh [NBLK,4H]
      (const float*)d_in[9],  // head_w [NINS,H]
      (const float*)d_in[10], // head_b [NINS]
      (float*)d_out);
}